// Round 2
// baseline (337.763 us; speedup 1.0000x reference)
//
#include <hip/hip_runtime.h>
#include <cmath>

constexpr int S = 160;
constexpr int BATCH = 4;

__device__ __forceinline__ float sigmoidf_(float x) {
  return 1.0f / (1.0f + expf(-x));
}

__global__ void init_q1(float* q1, int n) {
  int i = blockIdx.x * blockDim.x + threadIdx.x;
  if (i < n) q1[i] = 0.5f;
}

// One block per (b, m). 512 threads = 8 waves; wave w handles h = w, w+8, ...
// q1_in layout: [b][x][y] = q1[x, y, b] (fp32, B*S*S).
template <bool LAST>
__global__ __launch_bounds__(512) void mfvi_iter(
    const float* __restrict__ s_edge,   // [b][m][h]
    const float* __restrict__ s_sib,    // [b][m][h][t]
    const float* __restrict__ s_cop,
    const float* __restrict__ s_grd,
    const int* __restrict__ mask,       // [b][x][y] bool as int32
    const float* __restrict__ q1_in,
    float* __restrict__ q1_out,         // next q1, same layout (unused if LAST)
    float* __restrict__ outp) {         // [b][m][h][2] (used if LAST)
  const int m = blockIdx.x;
  const int b = blockIdx.y;
  const int tid = threadIdx.x;

  __shared__ float rowm[S];                 // q1[m, t, b]
  __shared__ float colm[S];                 // q1[t, m, b]
  __shared__ unsigned char mt[S * S];       // mt[h*S + t] = mask[b][t][h] != 0

  const float* G = q1_in + (size_t)b * S * S;
  const int* Mb = mask + (size_t)b * S * S;

  for (int t = tid; t < S; t += blockDim.x) {
    rowm[t] = G[m * S + t];
    colm[t] = G[t * S + m];
  }
  // coalesced global int32 read, transposed LDS write
  for (int i = tid; i < S * S; i += blockDim.x) {
    int t = i / S;
    int h = i - t * S;
    mt[h * S + t] = (Mb[i] != 0) ? 1 : 0;
  }
  __syncthreads();

  const int wave = tid >> 6;
  const int lane = tid & 63;
  const int nw = blockDim.x >> 6;
  const size_t base_bm = ((size_t)b * S + m) * S;

  for (int h = wave; h < S; h += nw) {
    const size_t rb = (base_bm + h) * S;
    const float* ssp = s_sib + rb;
    const float* scp = s_cop + rb;
    const float* sgp = s_grd + rb;
    const float* qh = G + h * S;  // q1[h, t, b]
    float acc = 0.f;
    for (int t = lane; t < S; t += 64) {
      float w = (mt[h * S + t] && t != h && t != m) ? 1.0f : 0.0f;
      acc += w * (qh[t] * ssp[t] + colm[t] * scp[t] + rowm[t] * sgp[t]);
    }
#pragma unroll
    for (int off = 32; off; off >>= 1) acc += __shfl_down(acc, off);
    if (lane == 0) {
      float pmh = (Mb[m * S + h] != 0) ? 1.0f : 0.0f;  // mask[b, m, h]
      float qv = s_edge[base_bm + h] + pmh * acc;
      if (!LAST) {
        // q1_next[h, m, b] -> layout [b][h][m]
        q1_out[((size_t)b * S + h) * S + m] = sigmoidf_(qv);
      } else {
        // out[b][m][h][c] = softmax([0, qv])[c]
        outp[(base_bm + h) * 2 + 0] = sigmoidf_(-qv);
        outp[(base_bm + h) * 2 + 1] = sigmoidf_(qv);
      }
    }
  }
}

extern "C" void kernel_launch(void* const* d_in, const int* in_sizes, int n_in,
                              void* d_out, int out_size, void* d_ws, size_t ws_size,
                              hipStream_t stream) {
  const float* s_edge = (const float*)d_in[0];
  const float* s_sib = (const float*)d_in[1];
  const float* s_cop = (const float*)d_in[2];
  const float* s_grd = (const float*)d_in[3];
  const int* mask = (const int*)d_in[4];
  float* outp = (float*)d_out;

  const int qn = BATCH * S * S;
  float* q1A = (float*)d_ws;
  float* q1B = q1A + qn;

  init_q1<<<(qn + 255) / 256, 256, 0, stream>>>(q1A, qn);

  dim3 grid(S, BATCH);
  // iter 1: q1 = 0.5 (A) -> B
  mfvi_iter<false><<<grid, 512, 0, stream>>>(s_edge, s_sib, s_cop, s_grd, mask,
                                             q1A, q1B, nullptr);
  // iter 2: B -> A
  mfvi_iter<false><<<grid, 512, 0, stream>>>(s_edge, s_sib, s_cop, s_grd, mask,
                                             q1B, q1A, nullptr);
  // iter 3: A -> out (probabilities)
  mfvi_iter<true><<<grid, 512, 0, stream>>>(s_edge, s_sib, s_cop, s_grd, mask,
                                            q1A, nullptr, outp);
}

// Round 3
// 262.875 us; speedup vs baseline: 1.2849x; 1.2849x over previous
//
#include <hip/hip_runtime.h>
#include <cmath>

constexpr int S = 160;
constexpr int BATCH = 4;
constexpr int S4 = S / 4;                  // 40 float4 chunks per row
constexpr int HALF = S / 2;                // 80 rows per z-block
constexpr int NW = 8;                      // waves per 512-thread block
constexpr int ROWS_PER_WAVE = HALF / NW;   // 10

__device__ __forceinline__ float sigmoidf_(float x) {
  return 1.0f / (1.0f + expf(-x));
}

// wf[b][h][t] = (mask[b][t][h] != 0 && t != h) ? 1 : 0   (byte)
__global__ void prep_wf(const int* __restrict__ mask, unsigned char* __restrict__ wf) {
  int i = blockIdx.x * blockDim.x + threadIdx.x;
  if (i >= BATCH * S * S) return;
  int t = i % S;
  int bh = i / S;
  int h = bh % S;
  int b = bh / S;
  wf[i] = (mask[(b * S + t) * S + h] != 0 && t != h) ? 1 : 0;
}

template <bool FIRST>
__device__ __forceinline__ float dot_row(unsigned wu, const float4& q,
                                         const float4& s, const float4& c,
                                         const float4& g, const float4& cm,
                                         const float4& rm) {
  float w0 = (float)(wu & 1u), w1 = (float)((wu >> 8) & 1u),
        w2 = (float)((wu >> 16) & 1u), w3 = (float)((wu >> 24) & 1u);
  float t0, t1, t2, t3;
  if (FIRST) {  // q1 == 0.5 for all three terms; factor 0.5 applied in epilogue
    t0 = s.x + c.x + g.x;
    t1 = s.y + c.y + g.y;
    t2 = s.z + c.z + g.z;
    t3 = s.w + c.w + g.w;
  } else {
    t0 = fmaf(q.x, s.x, fmaf(cm.x, c.x, rm.x * g.x));
    t1 = fmaf(q.y, s.y, fmaf(cm.y, c.y, rm.y * g.y));
    t2 = fmaf(q.z, s.z, fmaf(cm.z, c.z, rm.z * g.z));
    t3 = fmaf(q.w, s.w, fmaf(cm.w, c.w, rm.w * g.w));
  }
  return fmaf(w0, t0, fmaf(w1, t1, fmaf(w2, t2, w3 * t3)));
}

// One block per (b, m, half). 512 threads = 8 waves; wave w handles rows
// h = half*80 + w + 8k, k=0..9, two rows per round (fat float4 loads).
template <bool FIRST, bool LAST>
__global__ __launch_bounds__(512) void mfvi_iter(
    const float* __restrict__ s_edge,   // [b][m][h]
    const float* __restrict__ s_sib,    // [b][m][h][t]
    const float* __restrict__ s_cop,
    const float* __restrict__ s_grd,
    const int* __restrict__ mask,       // [b][x][y]
    const unsigned char* __restrict__ wf,  // [b][h][t]
    const float* __restrict__ q1_in,    // [b][x][y] = q1[x,y,b]
    float* __restrict__ q1_out,
    float* __restrict__ outp) {         // [b][m][h][2]
  const int m = blockIdx.x;
  const int b = blockIdx.y;
  const int half = blockIdx.z;
  const int tid = threadIdx.x;

  __shared__ __align__(16) float rowm[S];  // q1[m, t, b]
  __shared__ __align__(16) float colm[S];  // q1[t, m, b]
  __shared__ float sef[S];
  __shared__ float pmf[S];

  const float* G = q1_in + (size_t)b * S * S;
  const size_t bm = (size_t)b * S + m;

  if (tid < S) {
    sef[tid] = s_edge[bm * S + tid];
    pmf[tid] = (mask[bm * S + tid] != 0) ? 1.0f : 0.0f;
    if (!FIRST) {
      rowm[tid] = G[m * S + tid];
      colm[tid] = G[tid * S + m];
    }
  }
  __syncthreads();

  const int wave = tid >> 6;
  const int lane = tid & 63;
  const bool act = lane < S4;
  const int L = lane;

  float4 zero4 = make_float4(0.f, 0.f, 0.f, 0.f);
  float4 cm4 = zero4, rm4 = zero4;
  if (!FIRST && act) {
    cm4 = ((const float4*)colm)[L];
    rm4 = ((const float4*)rowm)[L];
  }

  const int h_base = half * HALF + wave;

#pragma unroll
  for (int j = 0; j < ROWS_PER_WAVE / 2; ++j) {
    const int h0 = h_base + NW * (2 * j);
    const int h1 = h0 + NW;
    float a0 = 0.f, a1 = 0.f;
    if (act) {
      const size_t r0 = (bm * S + h0) * S;
      const size_t r1 = (bm * S + h1) * S;
      unsigned w0u = ((const unsigned*)(wf + ((size_t)b * S + h0) * S))[L];
      unsigned w1u = ((const unsigned*)(wf + ((size_t)b * S + h1) * S))[L];
      float4 s0 = ((const float4*)(s_sib + r0))[L];
      float4 c0 = ((const float4*)(s_cop + r0))[L];
      float4 g0 = ((const float4*)(s_grd + r0))[L];
      float4 s1 = ((const float4*)(s_sib + r1))[L];
      float4 c1 = ((const float4*)(s_cop + r1))[L];
      float4 g1 = ((const float4*)(s_grd + r1))[L];
      float4 q0 = zero4, q1v = zero4;
      if (!FIRST) {
        q0 = ((const float4*)(G + h0 * S))[L];
        q1v = ((const float4*)(G + h1 * S))[L];
      }
      // fold t != m: clear byte (m&3) if this lane's chunk contains t == m
      if ((m >> 2) == L) {
        unsigned clr = ~(255u << ((m & 3) * 8));
        w0u &= clr;
        w1u &= clr;
      }
      a0 = dot_row<FIRST>(w0u, q0, s0, c0, g0, cm4, rm4);
      a1 = dot_row<FIRST>(w1u, q1v, s1, c1, g1, cm4, rm4);
    }
#pragma unroll
    for (int off = 32; off; off >>= 1) {
      a0 += __shfl_xor(a0, off);
      a1 += __shfl_xor(a1, off);
    }
    if (lane < 2) {
      const int h = (lane == 0) ? h0 : h1;
      const float acc = (lane == 0) ? a0 : a1;
      const float qv = fmaf(pmf[h], FIRST ? 0.5f * acc : acc, sef[h]);
      if (!LAST) {
        q1_out[((size_t)b * S + h) * S + m] = sigmoidf_(qv);
      } else {
        float2 o;
        o.x = sigmoidf_(-qv);
        o.y = sigmoidf_(qv);
        ((float2*)outp)[bm * S + h] = o;
      }
    }
  }
}

extern "C" void kernel_launch(void* const* d_in, const int* in_sizes, int n_in,
                              void* d_out, int out_size, void* d_ws, size_t ws_size,
                              hipStream_t stream) {
  const float* s_edge = (const float*)d_in[0];
  const float* s_sib = (const float*)d_in[1];
  const float* s_cop = (const float*)d_in[2];
  const float* s_grd = (const float*)d_in[3];
  const int* mask = (const int*)d_in[4];
  float* outp = (float*)d_out;

  const int qn = BATCH * S * S;
  float* q1A = (float*)d_ws;
  float* q1B = q1A + qn;
  unsigned char* wf = (unsigned char*)(q1B + qn);  // qn bytes

  prep_wf<<<(BATCH * S * S + 255) / 256, 256, 0, stream>>>(mask, wf);

  dim3 grid(S, BATCH, 2);
  // iter 1: q1 == 0.5 (analytic) -> q1B
  mfvi_iter<true, false><<<grid, 512, 0, stream>>>(
      s_edge, s_sib, s_cop, s_grd, mask, wf, q1A, q1B, nullptr);
  // iter 2: q1B -> q1A
  mfvi_iter<false, false><<<grid, 512, 0, stream>>>(
      s_edge, s_sib, s_cop, s_grd, mask, wf, q1B, q1A, nullptr);
  // iter 3: q1A -> out (probabilities)
  mfvi_iter<false, true><<<grid, 512, 0, stream>>>(
      s_edge, s_sib, s_cop, s_grd, mask, wf, q1A, nullptr, outp);
}

// Round 4
// 261.244 us; speedup vs baseline: 1.2929x; 1.0062x over previous
//
#include <hip/hip_runtime.h>
#include <cmath>

constexpr int S = 160;
constexpr int BATCH = 4;
constexpr int ZSPLIT = 2;
constexpr int ROWS = S / ZSPLIT;               // 80 rows per block
constexpr int KC = S / 4;                      // 40 float4-chunks per row
constexpr int CHUNKS = ROWS * KC;              // 3200 chunks per block
constexpr int TPB = 256;
constexpr int FULL_STEPS = CHUNKS / TPB;       // 12
constexpr int TAIL = CHUNKS - FULL_STEPS * TPB;// 128

__device__ __forceinline__ float sigmoidf_(float x) {
  return 1.0f / (1.0f + expf(-x));
}

// wf[b][h][t] = (mask[b][t][h] != 0 && t != h) ? 1 : 0   (byte)
__global__ void prep_wf(const int* __restrict__ mask, unsigned char* __restrict__ wf) {
  int i = blockIdx.x * blockDim.x + threadIdx.x;
  if (i >= BATCH * S * S) return;
  int t = i % S;
  int bh = i / S;
  int h = bh % S;
  int b = bh / S;
  wf[i] = (mask[(b * S + t) * S + h] != 0 && t != h) ? 1 : 0;
}

// One block per (b, m, zhalf). 256 threads stream 80 contiguous rows
// (3200 float4 chunks) of s_sib/s_cop/s_grd/q1/wf; per-chunk masked partials
// go to LDS; threads 0..79 then reduce one row each.
template <bool FIRST, bool LAST>
__global__ __launch_bounds__(TPB, 5) void mfvi_iter(
    const float* __restrict__ s_edge,   // [b][m][h]
    const float* __restrict__ s_sib,    // [b][m][h][t]
    const float* __restrict__ s_cop,
    const float* __restrict__ s_grd,
    const int* __restrict__ mask,       // [b][x][y]
    const unsigned char* __restrict__ wf,  // [b][h][t]
    const float* __restrict__ q1_in,    // [b][x][y] = q1[x,y,b]
    float* __restrict__ q1_out,
    float* __restrict__ outp) {         // [b][m][h][2]
  const int m = blockIdx.x;
  const int b = blockIdx.y;
  const int z = blockIdx.z;
  const int tid = threadIdx.x;

  __shared__ __align__(16) float part[CHUNKS];   // 12.8 KB
  __shared__ __align__(16) float colm[S];        // q1[t, m, b]
  __shared__ __align__(16) float rowm[S];        // q1[m, t, b]
  __shared__ float sef[ROWS];
  __shared__ float pmf[ROWS];

  const float* G = q1_in + (size_t)b * S * S;
  const size_t bm = (size_t)b * S + m;
  const int h0 = z * ROWS;

  if (tid < S) {
    if (!FIRST) {
      colm[tid] = G[tid * S + m];
      rowm[tid] = G[m * S + tid];
    }
    if (tid < ROWS) {
      sef[tid] = s_edge[bm * S + h0 + tid];
      pmf[tid] = (mask[bm * S + h0 + tid] != 0) ? 1.0f : 0.0f;
    }
  }
  __syncthreads();

  const size_t blk = (bm * S + h0) * (size_t)S;  // float offset of block region
  const float4* SS = (const float4*)(s_sib + blk);
  const float4* CC = (const float4*)(s_cop + blk);
  const float4* GG = (const float4*)(s_grd + blk);
  const float4* QQ = (const float4*)(G + h0 * S);
  const unsigned* WF = (const unsigned*)(wf + ((size_t)b * S + h0) * S);
  const int msel = m >> 2;
  const unsigned mclr = ~(255u << ((m & 3) * 8));

  auto body = [&](int c) {
    unsigned wu = WF[c];
    float4 s = SS[c];
    float4 cv = CC[c];
    float4 g = GG[c];
    int k = c % KC;                      // t-chunk within row
    if (k == msel) wu &= mclr;           // fold t != m
    float w0 = (float)(wu & 255u);
    float w1 = (float)((wu >> 8) & 255u);
    float w2 = (float)((wu >> 16) & 255u);
    float w3 = (float)(wu >> 24);
    float p;
    if (FIRST) {  // q1 == 0.5 everywhere; 0.5 factor applied in epilogue
      float t0 = s.x + cv.x + g.x;
      float t1 = s.y + cv.y + g.y;
      float t2 = s.z + cv.z + g.z;
      float t3 = s.w + cv.w + g.w;
      p = fmaf(w0, t0, fmaf(w1, t1, fmaf(w2, t2, w3 * t3)));
    } else {
      float4 q = QQ[c];
      float4 cm = ((const float4*)colm)[k];
      float4 rm = ((const float4*)rowm)[k];
      float t0 = fmaf(q.x, s.x, fmaf(cm.x, cv.x, rm.x * g.x));
      float t1 = fmaf(q.y, s.y, fmaf(cm.y, cv.y, rm.y * g.y));
      float t2 = fmaf(q.z, s.z, fmaf(cm.z, cv.z, rm.z * g.z));
      float t3 = fmaf(q.w, s.w, fmaf(cm.w, cv.w, rm.w * g.w));
      p = fmaf(w0, t0, fmaf(w1, t1, fmaf(w2, t2, w3 * t3)));
    }
    part[c] = p;
  };

  for (int step = 0; step < FULL_STEPS; ++step) body(step * TPB + tid);
  if (tid < TAIL) body(FULL_STEPS * TPB + tid);
  __syncthreads();

  if (tid < ROWS) {
    const float4* pr = (const float4*)part + tid * (KC / 4);
    float4 a = pr[0];
#pragma unroll
    for (int i = 1; i < KC / 4; ++i) {
      float4 v = pr[i];
      a.x += v.x; a.y += v.y; a.z += v.z; a.w += v.w;
    }
    float acc = (a.x + a.y) + (a.z + a.w);
    const int h = h0 + tid;
    const float qv = fmaf(pmf[tid], FIRST ? 0.5f * acc : acc, sef[tid]);
    if (!LAST) {
      q1_out[((size_t)b * S + h) * S + m] = sigmoidf_(qv);
    } else {
      float2 o;
      o.x = sigmoidf_(-qv);
      o.y = sigmoidf_(qv);
      ((float2*)outp)[bm * S + h] = o;
    }
  }
}

extern "C" void kernel_launch(void* const* d_in, const int* in_sizes, int n_in,
                              void* d_out, int out_size, void* d_ws, size_t ws_size,
                              hipStream_t stream) {
  const float* s_edge = (const float*)d_in[0];
  const float* s_sib = (const float*)d_in[1];
  const float* s_cop = (const float*)d_in[2];
  const float* s_grd = (const float*)d_in[3];
  const int* mask = (const int*)d_in[4];
  float* outp = (float*)d_out;

  const int qn = BATCH * S * S;
  float* q1A = (float*)d_ws;
  float* q1B = q1A + qn;
  unsigned char* wf = (unsigned char*)(q1B + qn);  // qn bytes

  prep_wf<<<(qn + 255) / 256, 256, 0, stream>>>(mask, wf);

  dim3 grid(S, BATCH, ZSPLIT);
  // iter 1: q1 == 0.5 (analytic) -> q1B
  mfvi_iter<true, false><<<grid, TPB, 0, stream>>>(
      s_edge, s_sib, s_cop, s_grd, mask, wf, q1A, q1B, nullptr);
  // iter 2: q1B -> q1A
  mfvi_iter<false, false><<<grid, TPB, 0, stream>>>(
      s_edge, s_sib, s_cop, s_grd, mask, wf, q1B, q1A, nullptr);
  // iter 3: q1A -> out (probabilities)
  mfvi_iter<false, true><<<grid, TPB, 0, stream>>>(
      s_edge, s_sib, s_cop, s_grd, mask, wf, q1A, nullptr, outp);
}